// Round 7
// baseline (76.583 us; speedup 1.0000x reference)
//
#include <hip/hip_runtime.h>

typedef unsigned int u32;

constexpr int B = 128, NN = 400, FEAT = 256, DEG = 64;
constexpr int N = B * NN;          // 51200
constexpr int E = B * NN * DEG;    // 3276800
constexpr int EPG = NN * DEG;      // 25600 edges per graph
constexpr int SPL = 4;             // edge splits per graph
constexpr int EPS = EPG / SPL;     // 6400 edges per split-block
constexpr int EPT = 13;            // ceil(EPS / 512) staged edges per thread
constexpr int BSTR = 47;           // bucket stride (odd -> bank-spread walks)
constexpr int BCAP = 46;           // bucket capacity; P(Poisson(16)>46)~2e-10

__device__ __forceinline__ float lrelu(float t) { return t > 0.f ? t : 0.01f * t; }

// K1: h0 = leaky_relu(x @ fc1_w.T + fc1_b)   [128,400]
__global__ void k_h0(const float* __restrict__ x, const float* __restrict__ fc1w,
                     const float* __restrict__ fc1b, float* __restrict__ h0g) {
    int b  = blockIdx.x >> 1;
    int nb = (blockIdx.x & 1) * 200;
    __shared__ float xs[FEAT];
    if (threadIdx.x < FEAT) xs[threadIdx.x] = x[b * FEAT + threadIdx.x];
    __syncthreads();
    if (threadIdx.x < 200) {
        int n = nb + threadIdx.x;
        const float4* w4 = reinterpret_cast<const float4*>(fc1w + n * FEAT);
        float s = 0.f;
        #pragma unroll 4
        for (int k4 = 0; k4 < FEAT / 4; ++k4) {
            float4 p = w4[k4];
            const float* xk = xs + k4 * 4;
            s += p.x * xk[0] + p.y * xk[1] + p.z * xk[2] + p.w * xk[3];
        }
        h0g[b * NN + n] = lrelu(s + fc1b[n]);
    }
}

// K2: single-atomic-pass bucketed sort + scan + compact flush + conv1 gather.
// Queue entry: (bf16(w) << 16) | src  -> 4 B/edge.
// grid 512 (b,sp), block 512
__global__ void __launch_bounds__(512, 2)
k_sort(const int* __restrict__ ei, const float* __restrict__ ea,
       const float* __restrict__ h0g,
       u32* __restrict__ sortedq, u32* __restrict__ qoff, u32* __restrict__ qcnt,
       float* __restrict__ agg1p) {
    int b = blockIdx.x >> 2, sp = blockIdx.x & 3;
    int boff = b * NN;
    __shared__ u32 bcnt[NN];
    __shared__ float h0s[NN];
    __shared__ u32 wsum[8];
    __shared__ u32 bucket[NN * BSTR];        // 75.2 KB

    int t = (int)threadIdx.x;
    if (t < NN) { bcnt[t] = 0u; h0s[t] = h0g[boff + t]; }

    // register-stage this thread's edges (single pass over ei/ea)
    int ebase = b * EPG + sp * EPS;
    int de[EPT];
    u32 pk[EPT];
    #pragma unroll
    for (int i = 0; i < EPT; ++i) {
        int idx = t + i * 512;
        de[i] = -1; pk[i] = 0u;
        if (idx < EPS) {
            int e = ebase + idx;
            int s = ei[e] - boff;
            de[i] = ei[E + e] - boff;
            u32 uw = __float_as_uint(ea[e]);
            u32 r = uw + 0x7fffu + ((uw >> 16) & 1u);   // rne to bf16
            pk[i] = (r & 0xffff0000u) | (u32)s;
        }
    }
    __syncthreads();

    // single atomic pass: claim slot, write bucket
    #pragma unroll
    for (int i = 0; i < EPT; ++i)
        if (de[i] >= 0) {
            u32 slot = atomicAdd(&bcnt[de[i]], 1u);
            if (slot < BCAP) bucket[de[i] * BSTR + slot] = pk[i];
        }
    __syncthreads();

    // exclusive scan of counts
    int lane = t & 63, wave = t >> 6;
    u32 c = (t < NN) ? min(bcnt[t], (u32)BCAP) : 0u;
    u32 x = c;
    #pragma unroll
    for (int d = 1; d < 64; d <<= 1) {
        u32 o = __shfl_up(x, d);
        if (lane >= d) x += o;
    }
    u32 wtot = __shfl(x, 63);
    if (lane == 0) wsum[wave] = wtot;
    __syncthreads();
    u32 wpre = 0;
    for (int w2 = 0; w2 < wave; ++w2) wpre += wsum[w2];
    u32 off = x + wpre - c;                  // exclusive scan (thread t owns node t)

    // compact flush + conv1 partial gather (own bucket run, bank-spread stride)
    if (t < NN) {
        qoff[sp * N + boff + t] = off;
        qcnt[sp * N + boff + t] = c;
        u32* gq = sortedq + (size_t)b * EPG + sp * EPS + off;
        const u32* bk = bucket + t * BSTR;
        float a = 0.f;
        for (u32 i = 0; i < c; ++i) {
            u32 p = bk[i];
            gq[i] = p;
            a += __uint_as_float(p & 0xffff0000u) * h0s[p & 0xffffu];
        }
        agg1p[sp * N + boff + t] = a;
    }
}

// K3: h1 compute (dup x4) + conv2 per-split gather -> agg2p partials.
// grid 512 (b,sp), block 512
__global__ void __launch_bounds__(512, 2)
k_g2(const u32* __restrict__ sortedq, const u32* __restrict__ qoff,
     const u32* __restrict__ qcnt, const float* __restrict__ agg1p,
     const float* __restrict__ h0g,
     const float* __restrict__ Wr1, const float* __restrict__ br1,
     const float* __restrict__ Wo1,
     float* __restrict__ h1g, float* __restrict__ cntg, float* __restrict__ agg2p) {
    int b = blockIdx.x >> 2, sp = blockIdx.x & 3;
    int boff = b * NN;
    __shared__ alignas(16) float h1s[NN * 8];   // 12.8 KB

    int t = (int)threadIdx.x;
    u32 myoff = 0, myc = 0;
    if (t < NN) {
        float a = 0.f; u32 ct = 0;
        #pragma unroll
        for (int s2 = 0; s2 < SPL; ++s2) {
            a  += agg1p[s2 * N + boff + t];
            u32 cc = qcnt[s2 * N + boff + t];
            ct += cc;
            if (s2 == sp) myc = cc;
        }
        myoff = qoff[sp * N + boff + t];
        float cf = (float)ct;
        a *= __builtin_amdgcn_rcpf(fmaxf(cf, 1.f));
        float h0 = h0g[boff + t];
        float v[8];
        #pragma unroll
        for (int k = 0; k < 8; ++k)
            v[k] = lrelu(a * Wr1[k] + br1[k] + h0 * Wo1[k]);
        float4* hl = reinterpret_cast<float4*>(h1s + t * 8);
        hl[0] = make_float4(v[0], v[1], v[2], v[3]);
        hl[1] = make_float4(v[4], v[5], v[6], v[7]);
        if (sp == 0) {
            float4* o = reinterpret_cast<float4*>(h1g + (size_t)(boff + t) * 8);
            o[0] = hl[0]; o[1] = hl[1];
            cntg[boff + t] = cf;
        }
    }
    __syncthreads();

    if (t < NN) {
        const u32* qp = sortedq + (size_t)b * EPG + sp * EPS + myoff;
        float acc[8];
        #pragma unroll
        for (int k = 0; k < 8; ++k) acc[k] = 0.f;
        for (u32 i = 0; i < myc; ++i) {
            u32 p = qp[i];
            float w = __uint_as_float(p & 0xffff0000u);
            const float4* hv = reinterpret_cast<const float4*>(h1s + (p & 0xffffu) * 8);
            float4 a0 = hv[0], a1 = hv[1];
            acc[0] += w * a0.x; acc[1] += w * a0.y; acc[2] += w * a0.z; acc[3] += w * a0.w;
            acc[4] += w * a1.x; acc[5] += w * a1.y; acc[6] += w * a1.z; acc[7] += w * a1.w;
        }
        float4* o = reinterpret_cast<float4*>(agg2p + ((size_t)sp * N + boff + t) * 8);
        o[0] = make_float4(acc[0], acc[1], acc[2], acc[3]);
        o[1] = make_float4(acc[4], acc[5], acc[6], acc[7]);
    }
}

// K4: out[b,i,j] = sigmoid(0.5*(z_i.m_j + z_j.m_i + bb[i] + bb[j]))
// 8x8 tiles; consecutive threads -> consecutive j-tiles (coalesced stores).
// grid 256 (128 graphs x 2 row-blocks of 200), block 512
__global__ void __launch_bounds__(512, 1)
k_out(const float* __restrict__ h1g, const float* __restrict__ agg2p,
      const float* __restrict__ cntg,
      const float* __restrict__ Wr2, const float* __restrict__ br2,
      const float* __restrict__ Wo2, float* __restrict__ out) {
    int b = blockIdx.x >> 1, rb = blockIdx.x & 1;
    __shared__ alignas(16) float Zt[16 * NN];
    __shared__ alignas(16) float Mt[16 * NN];
    __shared__ float bbs[NN];

    int j = threadIdx.x;
    if (j < NN) {
        int n = b * NN + j;
        float4 sA = make_float4(0, 0, 0, 0), sB = make_float4(0, 0, 0, 0);
        #pragma unroll
        for (int sp = 0; sp < SPL; ++sp) {
            const float4* ap = reinterpret_cast<const float4*>(agg2p + ((size_t)sp * N + n) * 8);
            float4 p0 = ap[0], p1 = ap[1];
            sA.x += p0.x; sA.y += p0.y; sA.z += p0.z; sA.w += p0.w;
            sB.x += p1.x; sB.y += p1.y; sB.z += p1.z; sB.w += p1.w;
        }
        float inv = __builtin_amdgcn_rcpf(fmaxf(cntg[n], 1.f));
        Zt[0 * NN + j] = sA.x * inv; Zt[1 * NN + j] = sA.y * inv;
        Zt[2 * NN + j] = sA.z * inv; Zt[3 * NN + j] = sA.w * inv;
        Zt[4 * NN + j] = sB.x * inv; Zt[5 * NN + j] = sB.y * inv;
        Zt[6 * NN + j] = sB.z * inv; Zt[7 * NN + j] = sB.w * inv;
        const float4* hv = reinterpret_cast<const float4*>(h1g + (size_t)n * 8);
        float4 h0v = hv[0], h1v = hv[1];
        Zt[ 8 * NN + j] = h0v.x; Zt[ 9 * NN + j] = h0v.y;
        Zt[10 * NN + j] = h0v.z; Zt[11 * NN + j] = h0v.w;
        Zt[12 * NN + j] = h1v.x; Zt[13 * NN + j] = h1v.y;
        Zt[14 * NN + j] = h1v.z; Zt[15 * NN + j] = h1v.w;
        const float* wr = Wr2 + j * 8;
        const float* wo = Wo2 + j * 8;
        #pragma unroll
        for (int k = 0; k < 8; ++k) {
            Mt[k * NN + j]       = wr[k];
            Mt[(8 + k) * NN + j] = wo[k];
        }
        bbs[j] = br2[j];
    }
    __syncthreads();

    for (int tau = threadIdx.x; tau < 25 * 50; tau += 512) {
        int ti = tau / 50, tj = tau % 50;         // consecutive lanes -> consecutive tj
        int i0 = rb * 200 + ti * 8;
        int j0 = tj * 8;
        float acc[8][8];
        #pragma unroll
        for (int r = 0; r < 8; ++r)
            #pragma unroll
            for (int cc = 0; cc < 8; ++cc) acc[r][cc] = 0.f;

        #pragma unroll
        for (int k = 0; k < 16; ++k) {
            const float* zr = Zt + k * NN;
            const float* mr = Mt + k * NN;
            float4 az0 = *reinterpret_cast<const float4*>(zr + i0);
            float4 az1 = *reinterpret_cast<const float4*>(zr + i0 + 4);
            float4 am0 = *reinterpret_cast<const float4*>(mr + i0);
            float4 am1 = *reinterpret_cast<const float4*>(mr + i0 + 4);
            float4 bz0 = *reinterpret_cast<const float4*>(zr + j0);
            float4 bz1 = *reinterpret_cast<const float4*>(zr + j0 + 4);
            float4 bm0 = *reinterpret_cast<const float4*>(mr + j0);
            float4 bm1 = *reinterpret_cast<const float4*>(mr + j0 + 4);
            float ar[8]  = {az0.x, az0.y, az0.z, az0.w, az1.x, az1.y, az1.z, az1.w};
            float amr[8] = {am0.x, am0.y, am0.z, am0.w, am1.x, am1.y, am1.z, am1.w};
            float bzv[8] = {bz0.x, bz0.y, bz0.z, bz0.w, bz1.x, bz1.y, bz1.z, bz1.w};
            float bmv[8] = {bm0.x, bm0.y, bm0.z, bm0.w, bm1.x, bm1.y, bm1.z, bm1.w};
            #pragma unroll
            for (int r = 0; r < 8; ++r)
                #pragma unroll
                for (int cc = 0; cc < 8; ++cc)
                    acc[r][cc] += ar[r] * bmv[cc] + amr[r] * bzv[cc];
        }

        float bi[8], bj[8];
        #pragma unroll
        for (int r = 0; r < 8; ++r) bi[r] = bbs[i0 + r];
        #pragma unroll
        for (int cc = 0; cc < 8; ++cc) bj[cc] = bbs[j0 + cc];

        size_t obase = (size_t)b * NN * NN;
        #pragma unroll
        for (int r = 0; r < 8; ++r) {
            float vout[8];
            #pragma unroll
            for (int cc = 0; cc < 8; ++cc) {
                float xv = 0.5f * (acc[r][cc] + bi[r] + bj[cc]);
                vout[cc] = __builtin_amdgcn_rcpf(1.f + __expf(-xv));
            }
            float* op = out + obase + (size_t)(i0 + r) * NN + j0;
            *reinterpret_cast<float4*>(op)     = make_float4(vout[0], vout[1], vout[2], vout[3]);
            *reinterpret_cast<float4*>(op + 4) = make_float4(vout[4], vout[5], vout[6], vout[7]);
        }
    }
}

extern "C" void kernel_launch(void* const* d_in, const int* in_sizes, int n_in,
                              void* d_out, int out_size, void* d_ws, size_t ws_size,
                              hipStream_t stream) {
    const float* x    = (const float*)d_in[0];
    const int*   ei   = (const int*)d_in[1];
    const float* ea   = (const float*)d_in[2];
    const float* fc1w = (const float*)d_in[3];
    const float* fc1b = (const float*)d_in[4];
    const float* Wr1  = (const float*)d_in[5];
    const float* br1  = (const float*)d_in[6];
    const float* Wo1  = (const float*)d_in[7];
    const float* Wr2  = (const float*)d_in[8];
    const float* br2  = (const float*)d_in[9];
    const float* Wo2  = (const float*)d_in[10];
    float* out = (float*)d_out;

    float* ws      = (float*)d_ws;
    float* h0g     = ws;                        // N
    float* h1g     = ws + N;                    // 8N
    float* cntg    = ws + 9 * N;                // N
    float* agg1p   = ws + 10 * N;               // 4N
    float* agg2p   = ws + 14 * N;               // 32N
    u32*   qoff    = (u32*)(ws + 46 * N);       // 4N
    u32*   qcnt    = (u32*)(ws + 50 * N);       // 4N
    u32*   sortedq = (u32*)(ws + 54 * N);       // E u32 = 13.1 MB (total ~24.2 MB)

    hipLaunchKernelGGL(k_h0,   dim3(256), dim3(256), 0, stream, x, fc1w, fc1b, h0g);
    hipLaunchKernelGGL(k_sort, dim3(512), dim3(512), 0, stream, ei, ea, h0g, sortedq, qoff, qcnt, agg1p);
    hipLaunchKernelGGL(k_g2,   dim3(512), dim3(512), 0, stream, sortedq, qoff, qcnt, agg1p, h0g, Wr1, br1, Wo1, h1g, cntg, agg2p);
    hipLaunchKernelGGL(k_out,  dim3(256), dim3(512), 0, stream, h1g, agg2p, cntg, Wr2, br2, Wo2, out);
}

// Round 8
// 74.672 us; speedup vs baseline: 1.0256x; 1.0256x over previous
//
#include <hip/hip_runtime.h>

typedef unsigned int u32;

constexpr int B = 128, NN = 400, FEAT = 256, DEG = 64;
constexpr int N = B * NN;          // 51200
constexpr int E = B * NN * DEG;    // 3276800
constexpr int EPG = NN * DEG;      // 25600 edges per graph
constexpr int SPL = 4;             // edge splits per graph
constexpr int EPS = EPG / SPL;     // 6400 edges per split-block
constexpr int EPT = 13;            // ceil(EPS / 512) staged edges per thread
constexpr int BSTR = 47;           // bucket stride (odd -> bank-spread walks)
constexpr int BCAP = 46;           // bucket capacity; P(Poisson(16)>46)~5e-10

__device__ __forceinline__ float lrelu(float t) { return t > 0.f ? t : 0.01f * t; }

// K1: h0 = leaky_relu(x @ fc1_w.T + fc1_b)   [128,400]
__global__ void k_h0(const float* __restrict__ x, const float* __restrict__ fc1w,
                     const float* __restrict__ fc1b, float* __restrict__ h0g) {
    int b  = blockIdx.x >> 1;
    int nb = (blockIdx.x & 1) * 200;
    __shared__ float xs[FEAT];
    if (threadIdx.x < FEAT) xs[threadIdx.x] = x[b * FEAT + threadIdx.x];
    __syncthreads();
    if (threadIdx.x < 200) {
        int n = nb + threadIdx.x;
        const float4* w4 = reinterpret_cast<const float4*>(fc1w + n * FEAT);
        float s = 0.f;
        #pragma unroll 4
        for (int k4 = 0; k4 < FEAT / 4; ++k4) {
            float4 p = w4[k4];
            const float* xk = xs + k4 * 4;
            s += p.x * xk[0] + p.y * xk[1] + p.z * xk[2] + p.w * xk[3];
        }
        h0g[b * NN + n] = lrelu(s + fc1b[n]);
    }
}

// K2: single-atomic-pass bucketed sort + scan + compact flush + conv1 gather.
// Queue entry: (bf16(w) << 16) | src  -> 4 B/edge.
// grid 512 (b,sp), block 512
__global__ void __launch_bounds__(512, 2)
k_sort(const int* __restrict__ ei, const float* __restrict__ ea,
       const float* __restrict__ h0g,
       u32* __restrict__ sortedq, u32* __restrict__ qoff, u32* __restrict__ qcnt,
       float* __restrict__ agg1p) {
    int b = blockIdx.x >> 2, sp = blockIdx.x & 3;
    int boff = b * NN;
    __shared__ u32 bcnt[NN];
    __shared__ float h0s[NN];
    __shared__ u32 wsum[8];
    __shared__ u32 bucket[NN * BSTR];        // 75.2 KB

    int t = (int)threadIdx.x;
    if (t < NN) { bcnt[t] = 0u; h0s[t] = h0g[boff + t]; }

    // register-stage this thread's edges (single pass over ei/ea)
    int ebase = b * EPG + sp * EPS;
    int de[EPT];
    u32 pk[EPT];
    #pragma unroll
    for (int i = 0; i < EPT; ++i) {
        int idx = t + i * 512;
        de[i] = -1; pk[i] = 0u;
        if (idx < EPS) {
            int e = ebase + idx;
            int s = ei[e] - boff;
            de[i] = ei[E + e] - boff;
            u32 uw = __float_as_uint(ea[e]);
            u32 r = uw + 0x7fffu + ((uw >> 16) & 1u);   // rne to bf16
            pk[i] = (r & 0xffff0000u) | (u32)s;
        }
    }
    __syncthreads();

    // single atomic pass: claim slot, write bucket
    #pragma unroll
    for (int i = 0; i < EPT; ++i)
        if (de[i] >= 0) {
            u32 slot = atomicAdd(&bcnt[de[i]], 1u);
            if (slot < BCAP) bucket[de[i] * BSTR + slot] = pk[i];
        }
    __syncthreads();

    // exclusive scan of counts
    int lane = t & 63, wave = t >> 6;
    u32 c = (t < NN) ? min(bcnt[t], (u32)BCAP) : 0u;
    u32 x = c;
    #pragma unroll
    for (int d = 1; d < 64; d <<= 1) {
        u32 o = __shfl_up(x, d);
        if (lane >= d) x += o;
    }
    u32 wtot = __shfl(x, 63);
    if (lane == 0) wsum[wave] = wtot;
    __syncthreads();
    u32 wpre = 0;
    for (int w2 = 0; w2 < wave; ++w2) wpre += wsum[w2];
    u32 off = x + wpre - c;                  // exclusive scan (thread t owns node t)

    // compact flush + conv1 partial gather (own bucket run, bank-spread stride)
    if (t < NN) {
        qoff[sp * N + boff + t] = off;
        qcnt[sp * N + boff + t] = c;
        u32* gq = sortedq + (size_t)b * EPG + sp * EPS + off;
        const u32* bk = bucket + t * BSTR;
        float a = 0.f;
        for (u32 i = 0; i < c; ++i) {
            u32 p = bk[i];
            gq[i] = p;
            a += __uint_as_float(p & 0xffff0000u) * h0s[p & 0xffffu];
        }
        agg1p[sp * N + boff + t] = a;
    }
}

// K3: h1 compute (dup x4) + conv2 per-split gather -> agg2p partials.
// grid 512 (b,sp), block 512
__global__ void __launch_bounds__(512, 2)
k_g2(const u32* __restrict__ sortedq, const u32* __restrict__ qoff,
     const u32* __restrict__ qcnt, const float* __restrict__ agg1p,
     const float* __restrict__ h0g,
     const float* __restrict__ Wr1, const float* __restrict__ br1,
     const float* __restrict__ Wo1,
     float* __restrict__ h1g, float* __restrict__ cntg, float* __restrict__ agg2p) {
    int b = blockIdx.x >> 2, sp = blockIdx.x & 3;
    int boff = b * NN;
    __shared__ alignas(16) float h1s[NN * 8];   // 12.8 KB

    int t = (int)threadIdx.x;
    u32 myoff = 0, myc = 0;
    if (t < NN) {
        float a = 0.f; u32 ct = 0;
        #pragma unroll
        for (int s2 = 0; s2 < SPL; ++s2) {
            a  += agg1p[s2 * N + boff + t];
            u32 cc = qcnt[s2 * N + boff + t];
            ct += cc;
            if (s2 == sp) myc = cc;
        }
        myoff = qoff[sp * N + boff + t];
        float cf = (float)ct;
        a *= __builtin_amdgcn_rcpf(fmaxf(cf, 1.f));
        float h0 = h0g[boff + t];
        float v[8];
        #pragma unroll
        for (int k = 0; k < 8; ++k)
            v[k] = lrelu(a * Wr1[k] + br1[k] + h0 * Wo1[k]);
        float4* hl = reinterpret_cast<float4*>(h1s + t * 8);
        hl[0] = make_float4(v[0], v[1], v[2], v[3]);
        hl[1] = make_float4(v[4], v[5], v[6], v[7]);
        if (sp == 0) {
            float4* o = reinterpret_cast<float4*>(h1g + (size_t)(boff + t) * 8);
            o[0] = hl[0]; o[1] = hl[1];
            cntg[boff + t] = cf;
        }
    }
    __syncthreads();

    if (t < NN) {
        const u32* qp = sortedq + (size_t)b * EPG + sp * EPS + myoff;
        float acc[8];
        #pragma unroll
        for (int k = 0; k < 8; ++k) acc[k] = 0.f;
        for (u32 i = 0; i < myc; ++i) {
            u32 p = qp[i];
            float w = __uint_as_float(p & 0xffff0000u);
            const float4* hv = reinterpret_cast<const float4*>(h1s + (p & 0xffffu) * 8);
            float4 a0 = hv[0], a1 = hv[1];
            acc[0] += w * a0.x; acc[1] += w * a0.y; acc[2] += w * a0.z; acc[3] += w * a0.w;
            acc[4] += w * a1.x; acc[5] += w * a1.y; acc[6] += w * a1.z; acc[7] += w * a1.w;
        }
        float4* o = reinterpret_cast<float4*>(agg2p + ((size_t)sp * N + boff + t) * 8);
        o[0] = make_float4(acc[0], acc[1], acc[2], acc[3]);
        o[1] = make_float4(acc[4], acc[5], acc[6], acc[7]);
    }
}

// K4: out[b,i,j] = sigmoid(0.5*(z_i.m_j + z_j.m_i + bb[i] + bb[j]))
// 4x8 tiles; consecutive threads -> consecutive j-tiles (coalesced stores);
// grid 512 (128 graphs x 4 row-blocks of 100) -> 2 blocks/CU, 16 waves/CU.
__global__ void __launch_bounds__(512, 4)
k_out(const float* __restrict__ h1g, const float* __restrict__ agg2p,
      const float* __restrict__ cntg,
      const float* __restrict__ Wr2, const float* __restrict__ br2,
      const float* __restrict__ Wo2, float* __restrict__ out) {
    int b = blockIdx.x >> 2, rb = blockIdx.x & 3;
    __shared__ alignas(16) float Zt[16 * NN];
    __shared__ alignas(16) float Mt[16 * NN];
    __shared__ float bbs[NN];

    int j = threadIdx.x;
    if (j < NN) {
        int n = b * NN + j;
        float4 sA = make_float4(0, 0, 0, 0), sB = make_float4(0, 0, 0, 0);
        #pragma unroll
        for (int sp = 0; sp < SPL; ++sp) {
            const float4* ap = reinterpret_cast<const float4*>(agg2p + ((size_t)sp * N + n) * 8);
            float4 p0 = ap[0], p1 = ap[1];
            sA.x += p0.x; sA.y += p0.y; sA.z += p0.z; sA.w += p0.w;
            sB.x += p1.x; sB.y += p1.y; sB.z += p1.z; sB.w += p1.w;
        }
        float inv = __builtin_amdgcn_rcpf(fmaxf(cntg[n], 1.f));
        Zt[0 * NN + j] = sA.x * inv; Zt[1 * NN + j] = sA.y * inv;
        Zt[2 * NN + j] = sA.z * inv; Zt[3 * NN + j] = sA.w * inv;
        Zt[4 * NN + j] = sB.x * inv; Zt[5 * NN + j] = sB.y * inv;
        Zt[6 * NN + j] = sB.z * inv; Zt[7 * NN + j] = sB.w * inv;
        const float4* hv = reinterpret_cast<const float4*>(h1g + (size_t)n * 8);
        float4 h0v = hv[0], h1v = hv[1];
        Zt[ 8 * NN + j] = h0v.x; Zt[ 9 * NN + j] = h0v.y;
        Zt[10 * NN + j] = h0v.z; Zt[11 * NN + j] = h0v.w;
        Zt[12 * NN + j] = h1v.x; Zt[13 * NN + j] = h1v.y;
        Zt[14 * NN + j] = h1v.z; Zt[15 * NN + j] = h1v.w;
        const float* wr = Wr2 + j * 8;
        const float* wo = Wo2 + j * 8;
        #pragma unroll
        for (int k = 0; k < 8; ++k) {
            Mt[k * NN + j]       = wr[k];
            Mt[(8 + k) * NN + j] = wo[k];
        }
        bbs[j] = br2[j];
    }
    __syncthreads();

    for (int tau = threadIdx.x; tau < 25 * 50; tau += 512) {
        int ti = tau / 50, tj = tau % 50;      // consecutive lanes -> consecutive tj
        int i0 = rb * 100 + ti * 4;
        int j0 = tj * 8;
        float acc[4][8];
        #pragma unroll
        for (int r = 0; r < 4; ++r)
            #pragma unroll
            for (int cc = 0; cc < 8; ++cc) acc[r][cc] = 0.f;

        #pragma unroll
        for (int k = 0; k < 16; ++k) {
            const float* zr = Zt + k * NN;
            const float* mr = Mt + k * NN;
            float4 az  = *reinterpret_cast<const float4*>(zr + i0);
            float4 am  = *reinterpret_cast<const float4*>(mr + i0);
            float4 bz0 = *reinterpret_cast<const float4*>(zr + j0);
            float4 bz1 = *reinterpret_cast<const float4*>(zr + j0 + 4);
            float4 bm0 = *reinterpret_cast<const float4*>(mr + j0);
            float4 bm1 = *reinterpret_cast<const float4*>(mr + j0 + 4);
            float ar[4]  = {az.x, az.y, az.z, az.w};
            float amr[4] = {am.x, am.y, am.z, am.w};
            float bzv[8] = {bz0.x, bz0.y, bz0.z, bz0.w, bz1.x, bz1.y, bz1.z, bz1.w};
            float bmv[8] = {bm0.x, bm0.y, bm0.z, bm0.w, bm1.x, bm1.y, bm1.z, bm1.w};
            #pragma unroll
            for (int r = 0; r < 4; ++r)
                #pragma unroll
                for (int cc = 0; cc < 8; ++cc)
                    acc[r][cc] += ar[r] * bmv[cc] + amr[r] * bzv[cc];
        }

        float bi[4], bj[8];
        #pragma unroll
        for (int r = 0; r < 4; ++r) bi[r] = bbs[i0 + r];
        #pragma unroll
        for (int cc = 0; cc < 8; ++cc) bj[cc] = bbs[j0 + cc];

        size_t obase = (size_t)b * NN * NN;
        #pragma unroll
        for (int r = 0; r < 4; ++r) {
            float vout[8];
            #pragma unroll
            for (int cc = 0; cc < 8; ++cc) {
                float xv = 0.5f * (acc[r][cc] + bi[r] + bj[cc]);
                vout[cc] = __builtin_amdgcn_rcpf(1.f + __expf(-xv));
            }
            float* op = out + obase + (size_t)(i0 + r) * NN + j0;
            *reinterpret_cast<float4*>(op)     = make_float4(vout[0], vout[1], vout[2], vout[3]);
            *reinterpret_cast<float4*>(op + 4) = make_float4(vout[4], vout[5], vout[6], vout[7]);
        }
    }
}

extern "C" void kernel_launch(void* const* d_in, const int* in_sizes, int n_in,
                              void* d_out, int out_size, void* d_ws, size_t ws_size,
                              hipStream_t stream) {
    const float* x    = (const float*)d_in[0];
    const int*   ei   = (const int*)d_in[1];
    const float* ea   = (const float*)d_in[2];
    const float* fc1w = (const float*)d_in[3];
    const float* fc1b = (const float*)d_in[4];
    const float* Wr1  = (const float*)d_in[5];
    const float* br1  = (const float*)d_in[6];
    const float* Wo1  = (const float*)d_in[7];
    const float* Wr2  = (const float*)d_in[8];
    const float* br2  = (const float*)d_in[9];
    const float* Wo2  = (const float*)d_in[10];
    float* out = (float*)d_out;

    float* ws      = (float*)d_ws;
    float* h0g     = ws;                        // N
    float* h1g     = ws + N;                    // 8N
    float* cntg    = ws + 9 * N;                // N
    float* agg1p   = ws + 10 * N;               // 4N
    float* agg2p   = ws + 14 * N;               // 32N
    u32*   qoff    = (u32*)(ws + 46 * N);       // 4N
    u32*   qcnt    = (u32*)(ws + 50 * N);       // 4N
    u32*   sortedq = (u32*)(ws + 54 * N);       // E u32 = 13.1 MB (total ~24.2 MB)

    hipLaunchKernelGGL(k_h0,   dim3(256), dim3(256), 0, stream, x, fc1w, fc1b, h0g);
    hipLaunchKernelGGL(k_sort, dim3(512), dim3(512), 0, stream, ei, ea, h0g, sortedq, qoff, qcnt, agg1p);
    hipLaunchKernelGGL(k_g2,   dim3(512), dim3(512), 0, stream, sortedq, qoff, qcnt, agg1p, h0g, Wr1, br1, Wo1, h1g, cntg, agg2p);
    hipLaunchKernelGGL(k_out,  dim3(512), dim3(512), 0, stream, h1g, agg2p, cntg, Wr2, br2, Wo2, out);
}